// Round 9
// baseline (119.411 us; speedup 1.0000x reference)
//
#include <hip/hip_runtime.h>
#include <math.h>

// SpatialEncodeAgent: segment_max of agent_encodings (N,64) into a B*100*100
// grid, output [B, C, S, S] f32, 0 for empty cells.
//
// Round-9: round-8 (LL build + 8 chains per 16-lane group, 32 chains/wave,
// ~8KB in flight) with the output-write bug fixed: round-8's second write
// loop covered c=[32..95] over the FULL tile range -> wrote channels 64..95,
// i.e. out of this batch's plane (absmax 96). Now a single loop covers the
// 128x64 tile exactly. Evidence trail: gather BW scaled with chains/wave
// (1 -> 1.0 TB/s, 4 -> ~3.5, 16 -> ~4.4); latency/MLP-bound, so raise
// independent loads in flight. All loads issue unconditionally (dead chains
// clamp to row 0, L1-resident). enc loads cacheable (cross-replay L3
// retention); output stores nontemporal.
// fmax is exactly commutative -> chain-order nondeterminism is bitwise-safe.

#define S_DIM 100
#define CELLS_PER_B (S_DIM * S_DIM)  // 10000
#define C_DIM 64
#define NCH 8    // chains per 16-lane group
#define CPB 128  // cells per block = 16 groups * NCH

typedef float fvec4 __attribute__((ext_vector_type(4)));

__device__ __forceinline__ fvec4 max4(fvec4 a, fvec4 b) {
    fvec4 r;
    r.x = fmaxf(a.x, b.x);
    r.y = fmaxf(a.y, b.y);
    r.z = fmaxf(a.z, b.z);
    r.w = fmaxf(a.w, b.w);
    return r;
}

__global__ void init_head(int* __restrict__ head, int n) {
    const int stride = gridDim.x * blockDim.x;
    for (int i = blockIdx.x * blockDim.x + threadIdx.x; i < n; i += stride)
        head[i] = -1;
}

__global__ void build_lists(const int* __restrict__ coords,
                            int* __restrict__ head, int* __restrict__ next,
                            int n) {
    const int n4 = n >> 2;
    const int stride = gridDim.x * blockDim.x;
    const int4* c4p = reinterpret_cast<const int4*>(coords);
    for (int i = blockIdx.x * blockDim.x + threadIdx.x; i < n4; i += stride) {
        const int4 c = c4p[i];
        const int base = i << 2;
        int4 nx;
        nx.x = atomicExch(&head[c.x], base + 0);
        nx.y = atomicExch(&head[c.y], base + 1);
        nx.z = atomicExch(&head[c.z], base + 2);
        nx.w = atomicExch(&head[c.w], base + 3);
        reinterpret_cast<int4*>(next)[i] = nx;  // coalesced
    }
    const int tail0 = n4 << 2;
    const int g = blockIdx.x * blockDim.x + threadIdx.x;
    if (g < n - tail0) {
        const int i = tail0 + g;
        next[i] = atomicExch(&head[coords[i]], i);
    }
}

// Block = 256 threads = 16 groups of 16 lanes; each group walks NCH=8 chains
// (8 consecutive cells). Lane owns 4 channels (float4 of the 256B row).
// Grid: x = ceil(10000/CPB) chunks within a batch plane, y = batch.
__global__ __launch_bounds__(256) void gather_ll8(
    const float* __restrict__ enc, const int* __restrict__ head,
    const int* __restrict__ next, float* __restrict__ out) {
    __shared__ float tile[CPB][C_DIM + 1];  // +1 pad: conflict-free transpose
    const int tid = threadIdx.x;
    const int grp = tid >> 4;  // 0..15
    const int l16 = tid & 15;
    const int b = blockIdx.y;
    const int rem0 = blockIdx.x * CPB;
    const int cbase = rem0 + grp * NCH;  // first of this group's 8 cells
    const long long cell0 = (long long)b * CELLS_PER_B + cbase;

    int a[NCH];
    bool occ[NCH];
#pragma unroll
    for (int k = 0; k < NCH; ++k) {
        a[k] = (cbase + k < CELLS_PER_B) ? head[cell0 + k] : -1;
        occ[k] = (a[k] >= 0);
    }

    const fvec4* enc4 = reinterpret_cast<const fvec4*>(enc);
    fvec4 m[NCH];
#pragma unroll
    for (int k = 0; k < NCH; ++k)
        m[k] = (fvec4){-INFINITY, -INFINITY, -INFINITY, -INFINITY};

    for (;;) {
        bool any = false;
#pragma unroll
        for (int k = 0; k < NCH; ++k) any = any || (a[k] >= 0);
        if (!any) break;

        int idx[NCH], nx[NCH];
        fvec4 v[NCH];
#pragma unroll
        for (int k = 0; k < NCH; ++k) idx[k] = a[k] >= 0 ? a[k] : 0;
#pragma unroll
        for (int k = 0; k < NCH; ++k) nx[k] = next[idx[k]];
#pragma unroll
        for (int k = 0; k < NCH; ++k) v[k] = enc4[(size_t)idx[k] * 16 + l16];
#pragma unroll
        for (int k = 0; k < NCH; ++k) {
            if (a[k] >= 0) {
                m[k] = max4(m[k], v[k]);
                a[k] = nx[k];
            }
        }
    }

#pragma unroll
    for (int k = 0; k < NCH; ++k) {
        if (!occ[k]) m[k] = (fvec4){0.f, 0.f, 0.f, 0.f};
        const int r = grp * NCH + k;
        const int cb = l16 << 2;
        tile[r][cb + 0] = m[k].x;
        tile[r][cb + 1] = m[k].y;
        tile[r][cb + 2] = m[k].z;
        tile[r][cb + 3] = m[k].w;
    }
    __syncthreads();

    // Transposed write: single loop over the 128x64 tile. Per channel c,
    // 64 consecutive lanes store 64 consecutive cells (256B segments; rem0 is
    // a multiple of 128 -> line-aligned). Nontemporal to keep out-lines from
    // evicting enc in L3 (enc has cross-replay reuse).
    float* base = out + ((size_t)b * C_DIM) * CELLS_PER_B + rem0;
    const int limit = min(CPB, CELLS_PER_B - rem0);
    for (int i = tid; i < CPB * C_DIM; i += 256) {
        const int c = i >> 7;   // channel 0..63
        const int j = i & 127;  // cell 0..127
        if (j < limit)
            __builtin_nontemporal_store(tile[j][c],
                                        &base[(size_t)c * CELLS_PER_B + j]);
    }
}

// ---------- fallback (atomic scatter) if ws too small ----------
__device__ __forceinline__ unsigned encode_f32(float f) {
    unsigned u = __float_as_uint(f);
    return (u & 0x80000000u) ? ~u : (u | 0x80000000u);
}
__device__ __forceinline__ float decode_key(unsigned k) {
    if (k == 0u) return 0.0f;
    return (k & 0x80000000u) ? __uint_as_float(k & 0x7FFFFFFFu)
                             : __uint_as_float(~k);
}
__global__ void spatial_scatter_max(const float* __restrict__ enc,
                                    const int* __restrict__ coords,
                                    unsigned* __restrict__ grid, int n_agents) {
    const long long total = (long long)n_agents * 16;
    const long long stride = (long long)gridDim.x * blockDim.x;
    for (long long i = (long long)blockIdx.x * blockDim.x + threadIdx.x;
         i < total; i += stride) {
        const int agent = (int)(i >> 4);
        const int c4 = ((int)i & 15) << 2;
        const int coord = coords[agent];
        const int b = coord / CELLS_PER_B;
        const int rem = coord - b * CELLS_PER_B;
        const float4 v =
            *reinterpret_cast<const float4*>(enc + (size_t)agent * C_DIM + c4);
        unsigned* p = grid + ((size_t)b * C_DIM + c4) * CELLS_PER_B + rem;
        atomicMax(p, encode_f32(v.x));
        atomicMax(p + 1 * CELLS_PER_B, encode_f32(v.y));
        atomicMax(p + 2 * CELLS_PER_B, encode_f32(v.z));
        atomicMax(p + 3 * CELLS_PER_B, encode_f32(v.w));
    }
}
__global__ void spatial_decode(unsigned* __restrict__ grid, int n4) {
    const int stride = gridDim.x * blockDim.x;
    uint4* g4 = reinterpret_cast<uint4*>(grid);
    for (int i = blockIdx.x * blockDim.x + threadIdx.x; i < n4; i += stride) {
        uint4 k = g4[i];
        float4 f;
        f.x = decode_key(k.x);
        f.y = decode_key(k.y);
        f.z = decode_key(k.z);
        f.w = decode_key(k.w);
        reinterpret_cast<float4*>(g4)[i] = f;
    }
}

extern "C" void kernel_launch(void* const* d_in, const int* in_sizes, int n_in,
                              void* d_out, int out_size, void* d_ws, size_t ws_size,
                              hipStream_t stream) {
    const float* enc = (const float*)d_in[1];
    const int* coords = (const int*)d_in[2];
    const int n = in_sizes[2];
    const int ncells = out_size / C_DIM;  // B * 10000
    const int B = ncells / CELLS_PER_B;

    const size_t need = ((size_t)ncells + (size_t)n) * sizeof(int);
    if (ws_size >= need) {
        int* head = (int*)d_ws;
        int* next = head + ncells;
        init_head<<<512, 256, 0, stream>>>(head, ncells);
        build_lists<<<1024, 256, 0, stream>>>(coords, head, next, n);
        dim3 grid((CELLS_PER_B + CPB - 1) / CPB, B);  // (79, B)
        gather_ll8<<<grid, 256, 0, stream>>>(enc, head, next, (float*)d_out);
    } else {
        unsigned* out = (unsigned*)d_out;
        hipMemsetAsync(d_out, 0, (size_t)out_size * sizeof(float), stream);
        spatial_scatter_max<<<2048, 256, 0, stream>>>(enc, coords, out, n);
        spatial_decode<<<2048, 256, 0, stream>>>(out, out_size / 4);
    }
}

// Round 10
// 116.546 us; speedup vs baseline: 1.0246x; 1.0246x over previous
//
#include <hip/hip_runtime.h>
#include <math.h>

// SpatialEncodeAgent: segment_max of agent_encodings (N,64) into a B*100*100
// grid, output [B, C, S, S] f32, 0 for empty cells.
//
// Round-10: revert to the measured-best round-7 configuration (117.0 us).
// Mechanism summary (established over rounds 1-9):
//  - scatter-atomics over the 82MB output thrash L2 (round 1: 2GB WRITE_SIZE,
//    2431 us) -> invert to per-cell linked-list gather.
//  - the gather is LATENCY/MLP-bound, not BW-bound (round 5: 1 chain/wave =
//    1.0 TB/s at 85% occupancy). Effective BW scales with independent loads
//    in flight per wave: 1 chain -> 1.0 TB/s, 4 -> ~3.5, 16 -> ~4.4,
//    32 -> ~4.3 (plateau) => 16 chains/wave (NCH=4 per 16-lane group) sits
//    at the random-256B-read concurrency ceiling (~4.3 TB/s effective).
//  - sorting to make enc reads sequential costs more than it saves
//    (round 4 CSR: +85 us; round 6 buckets: +38 us of scattered-write RFO).
//  - loop body issues all 8 loads (4 next + 4 enc rows) UNCONDITIONALLY
//    (dead chains clamp to row 0, L1-resident) before any consumer.
//  - enc loads stay cacheable (cross-replay L3 retention: FETCH 174MB <
//    256MB enc); output stores nontemporal to protect that retention.
// fmax is exactly commutative -> chain-order nondeterminism is bitwise-safe.

#define S_DIM 100
#define CELLS_PER_B (S_DIM * S_DIM)  // 10000
#define C_DIM 64
#define CPB 64  // cells per gather block (256 thr = 16 groups x 4 chains)

typedef float fvec4 __attribute__((ext_vector_type(4)));

__device__ __forceinline__ fvec4 max4(fvec4 a, fvec4 b) {
    fvec4 r;
    r.x = fmaxf(a.x, b.x);
    r.y = fmaxf(a.y, b.y);
    r.z = fmaxf(a.z, b.z);
    r.w = fmaxf(a.w, b.w);
    return r;
}

__global__ void init_head(int* __restrict__ head, int n) {
    const int stride = gridDim.x * blockDim.x;
    for (int i = blockIdx.x * blockDim.x + threadIdx.x; i < n; i += stride)
        head[i] = -1;
}

__global__ void build_lists(const int* __restrict__ coords,
                            int* __restrict__ head, int* __restrict__ next,
                            int n) {
    const int n4 = n >> 2;
    const int stride = gridDim.x * blockDim.x;
    const int4* c4p = reinterpret_cast<const int4*>(coords);
    for (int i = blockIdx.x * blockDim.x + threadIdx.x; i < n4; i += stride) {
        const int4 c = c4p[i];
        const int base = i << 2;
        int4 nx;
        nx.x = atomicExch(&head[c.x], base + 0);
        nx.y = atomicExch(&head[c.y], base + 1);
        nx.z = atomicExch(&head[c.z], base + 2);
        nx.w = atomicExch(&head[c.w], base + 3);
        reinterpret_cast<int4*>(next)[i] = nx;  // coalesced
    }
    const int tail0 = n4 << 2;
    const int g = blockIdx.x * blockDim.x + threadIdx.x;
    if (g < n - tail0) {
        const int i = tail0 + g;
        next[i] = atomicExch(&head[coords[i]], i);
    }
}

// Block = 256 threads = 16 groups of 16 lanes; each group walks 4 chains
// (4 consecutive cells). Lane owns 4 channels (float4 of the 256B row).
// Grid: x = ceil(10000/CPB) chunks within a batch plane, y = batch.
__global__ __launch_bounds__(256) void gather_ll4(
    const float* __restrict__ enc, const int* __restrict__ head,
    const int* __restrict__ next, float* __restrict__ out) {
    __shared__ float tile[CPB][C_DIM + 1];  // +1 pad: conflict-free transpose
    const int tid = threadIdx.x;
    const int grp = tid >> 4;  // 0..15
    const int l16 = tid & 15;
    const int b = blockIdx.y;
    const int rem0 = blockIdx.x * CPB;
    const int cbase = rem0 + (grp << 2);  // first of this group's 4 cells
    const long long cell0 = (long long)b * CELLS_PER_B + cbase;

    int a0 = (cbase + 0 < CELLS_PER_B) ? head[cell0 + 0] : -1;
    int a1 = (cbase + 1 < CELLS_PER_B) ? head[cell0 + 1] : -1;
    int a2 = (cbase + 2 < CELLS_PER_B) ? head[cell0 + 2] : -1;
    int a3 = (cbase + 3 < CELLS_PER_B) ? head[cell0 + 3] : -1;
    const bool o0 = a0 >= 0, o1 = a1 >= 0, o2 = a2 >= 0, o3 = a3 >= 0;

    const fvec4* enc4 = reinterpret_cast<const fvec4*>(enc);
    fvec4 m0 = {-INFINITY, -INFINITY, -INFINITY, -INFINITY};
    fvec4 m1 = m0, m2 = m0, m3 = m0;

    while (a0 >= 0 || a1 >= 0 || a2 >= 0 || a3 >= 0) {
        // clamp dead chains to row 0 so ALL loads issue unconditionally
        const int i0 = a0 >= 0 ? a0 : 0;
        const int i1 = a1 >= 0 ? a1 : 0;
        const int i2 = a2 >= 0 ? a2 : 0;
        const int i3 = a3 >= 0 ? a3 : 0;
        const int n0 = next[i0];
        const int n1 = next[i1];
        const int n2 = next[i2];
        const int n3 = next[i3];
        const fvec4 v0 = enc4[(size_t)i0 * 16 + l16];
        const fvec4 v1 = enc4[(size_t)i1 * 16 + l16];
        const fvec4 v2 = enc4[(size_t)i2 * 16 + l16];
        const fvec4 v3 = enc4[(size_t)i3 * 16 + l16];
        if (a0 >= 0) { m0 = max4(m0, v0); a0 = n0; }
        if (a1 >= 0) { m1 = max4(m1, v1); a1 = n1; }
        if (a2 >= 0) { m2 = max4(m2, v2); a2 = n2; }
        if (a3 >= 0) { m3 = max4(m3, v3); a3 = n3; }
    }
    if (!o0) m0 = (fvec4){0.f, 0.f, 0.f, 0.f};
    if (!o1) m1 = (fvec4){0.f, 0.f, 0.f, 0.f};
    if (!o2) m2 = (fvec4){0.f, 0.f, 0.f, 0.f};
    if (!o3) m3 = (fvec4){0.f, 0.f, 0.f, 0.f};

    const int r = grp << 2;
    const int cb = l16 << 2;
    tile[r + 0][cb + 0] = m0.x; tile[r + 0][cb + 1] = m0.y;
    tile[r + 0][cb + 2] = m0.z; tile[r + 0][cb + 3] = m0.w;
    tile[r + 1][cb + 0] = m1.x; tile[r + 1][cb + 1] = m1.y;
    tile[r + 1][cb + 2] = m1.z; tile[r + 1][cb + 3] = m1.w;
    tile[r + 2][cb + 0] = m2.x; tile[r + 2][cb + 1] = m2.y;
    tile[r + 2][cb + 2] = m2.z; tile[r + 2][cb + 3] = m2.w;
    tile[r + 3][cb + 0] = m3.x; tile[r + 3][cb + 1] = m3.y;
    tile[r + 3][cb + 2] = m3.z; tile[r + 3][cb + 3] = m3.w;
    __syncthreads();

    // Transposed write: per channel c, 64 lanes store 64 consecutive cells
    // (256B, line-aligned since rem0 is a multiple of 64). Nontemporal to
    // keep out-lines from evicting enc in L3.
    float* base = out + ((size_t)b * C_DIM) * CELLS_PER_B + rem0;
    const int limit = min(CPB, CELLS_PER_B - rem0);
    for (int i = tid; i < CPB * C_DIM; i += 256) {
        const int c = i >> 6;
        const int j = i & 63;
        if (j < limit)
            __builtin_nontemporal_store(tile[j][c],
                                        &base[(size_t)c * CELLS_PER_B + j]);
    }
}

// ---------- fallback (atomic scatter) if ws too small ----------
__device__ __forceinline__ unsigned encode_f32(float f) {
    unsigned u = __float_as_uint(f);
    return (u & 0x80000000u) ? ~u : (u | 0x80000000u);
}
__device__ __forceinline__ float decode_key(unsigned k) {
    if (k == 0u) return 0.0f;
    return (k & 0x80000000u) ? __uint_as_float(k & 0x7FFFFFFFu)
                             : __uint_as_float(~k);
}
__global__ void spatial_scatter_max(const float* __restrict__ enc,
                                    const int* __restrict__ coords,
                                    unsigned* __restrict__ grid, int n_agents) {
    const long long total = (long long)n_agents * 16;
    const long long stride = (long long)gridDim.x * blockDim.x;
    for (long long i = (long long)blockIdx.x * blockDim.x + threadIdx.x;
         i < total; i += stride) {
        const int agent = (int)(i >> 4);
        const int c4 = ((int)i & 15) << 2;
        const int coord = coords[agent];
        const int b = coord / CELLS_PER_B;
        const int rem = coord - b * CELLS_PER_B;
        const float4 v =
            *reinterpret_cast<const float4*>(enc + (size_t)agent * C_DIM + c4);
        unsigned* p = grid + ((size_t)b * C_DIM + c4) * CELLS_PER_B + rem;
        atomicMax(p, encode_f32(v.x));
        atomicMax(p + 1 * CELLS_PER_B, encode_f32(v.y));
        atomicMax(p + 2 * CELLS_PER_B, encode_f32(v.z));
        atomicMax(p + 3 * CELLS_PER_B, encode_f32(v.w));
    }
}
__global__ void spatial_decode(unsigned* __restrict__ grid, int n4) {
    const int stride = gridDim.x * blockDim.x;
    uint4* g4 = reinterpret_cast<uint4*>(grid);
    for (int i = blockIdx.x * blockDim.x + threadIdx.x; i < n4; i += stride) {
        uint4 k = g4[i];
        float4 f;
        f.x = decode_key(k.x);
        f.y = decode_key(k.y);
        f.z = decode_key(k.z);
        f.w = decode_key(k.w);
        reinterpret_cast<float4*>(g4)[i] = f;
    }
}

extern "C" void kernel_launch(void* const* d_in, const int* in_sizes, int n_in,
                              void* d_out, int out_size, void* d_ws, size_t ws_size,
                              hipStream_t stream) {
    const float* enc = (const float*)d_in[1];
    const int* coords = (const int*)d_in[2];
    const int n = in_sizes[2];
    const int ncells = out_size / C_DIM;  // B * 10000
    const int B = ncells / CELLS_PER_B;

    const size_t need = ((size_t)ncells + (size_t)n) * sizeof(int);
    if (ws_size >= need) {
        int* head = (int*)d_ws;
        int* next = head + ncells;
        init_head<<<512, 256, 0, stream>>>(head, ncells);
        build_lists<<<1024, 256, 0, stream>>>(coords, head, next, n);
        dim3 grid((CELLS_PER_B + CPB - 1) / CPB, B);  // (157, B)
        gather_ll4<<<grid, 256, 0, stream>>>(enc, head, next, (float*)d_out);
    } else {
        unsigned* out = (unsigned*)d_out;
        hipMemsetAsync(d_out, 0, (size_t)out_size * sizeof(float), stream);
        spatial_scatter_max<<<2048, 256, 0, stream>>>(enc, coords, out, n);
        spatial_decode<<<2048, 256, 0, stream>>>(out, out_size / 4);
    }
}